// Round 1
// baseline (181.679 us; speedup 1.0000x reference)
//
#include <hip/hip_runtime.h>
#include <math.h>

#define BB 32
#define CC 256
#define CQ 32      // C/8
#define NN 1024    // H*W

typedef short bf16x8 __attribute__((ext_vector_type(8)));
typedef float f32x4  __attribute__((ext_vector_type(4)));
typedef unsigned short u16;

// fp32 -> bf16 RNE
__device__ __forceinline__ u16 f2bf(float f) {
    unsigned u = __float_as_uint(f);
    u = (u + 0x7FFFu + ((u >> 16) & 1u)) >> 16;
    return (u16)u;
}

// ---------------------------------------------------------------------------
// Kernel 0: pack fused W = [Wq(32); Wk(32); Wv(256)] into MFMA A-frag order:
// wfrag[((rt*8 + kc)*64 + lane)*8 + j] = W[rt*16 + (lane&15)][kc*32 + (lane>>4)*8 + j]
// ---------------------------------------------------------------------------
__global__ void wpack_kernel(const float* __restrict__ Wq,
                             const float* __restrict__ Wk,
                             const float* __restrict__ Wv,
                             u16* __restrict__ wfrag)
{
    const int o = blockIdx.x * 256 + threadIdx.x;     // 0 .. 81919
    const int j    = o & 7;
    const int lane = (o >> 3) & 63;
    const int kc   = (o >> 9) & 7;
    const int rt   = o >> 12;                         // 0..19
    const int row  = rt * 16 + (lane & 15);
    const int col  = kc * 32 + (lane >> 4) * 8 + j;
    const float v = (row < 32) ? Wq[row * 256 + col]
                  : (row < 64) ? Wk[(row - 32) * 256 + col]
                               : Wv[(row - 64) * 256 + col];
    wfrag[o] = f2bf(v);
}

// ---------------------------------------------------------------------------
// Kernel 1: QKV projection via MFMA. grid(16 n-tiles, 32 b), 256 thr.
// qt,kt: [b][n][32 d] bf16 ; vv: [b][c][n] bf16. All global I/O coalesced.
// Staging: 16 float4 loads all in flight (no dep clusters, no spill).
// ---------------------------------------------------------------------------
struct QSmem {
    union {
        u16 xs[64][272];     // x^T tile [n][c] bf16
        u16 osv[CC][72];     // v result [c][n]
    };
    u16 osqk[64][72];        // q|k result [n][d], d 0..31 = q, 32..63 = k
};

__global__ __launch_bounds__(256, 2) void qkv_kernel(
    const float* __restrict__ x, const u16* __restrict__ wfrag,
    const float* __restrict__ bq, const float* __restrict__ bk,
    const float* __restrict__ bv,
    u16* __restrict__ qt, u16* __restrict__ kt, u16* __restrict__ vv)
{
    __shared__ QSmem sm;
    const int b = blockIdx.y, n0 = blockIdx.x * 64;
    const int t = threadIdx.x;
    const int lane = t & 63, w = t >> 6;
    const int quad = lane >> 4, c16 = lane & 15;

    // ---- stage x^T bf16: 16 coalesced float4 loads, then transpose-pack
    {
        const float* xb = x + (size_t)b * CC * NN + n0;
        const int cg = t >> 4;            // 0..15: c within group of 16
        const int n4 = (t & 15) * 4;      // n quad
        float4 f[16];
#pragma unroll
        for (int it = 0; it < 16; ++it)
            f[it] = *(const float4*)(xb + (size_t)(it * 16 + cg) * NN + n4);
#pragma unroll
        for (int it = 0; it < 16; ++it) {
            const int c = it * 16 + cg;
            sm.xs[n4 + 0][c] = f2bf(f[it].x);
            sm.xs[n4 + 1][c] = f2bf(f[it].y);
            sm.xs[n4 + 2][c] = f2bf(f[it].z);
            sm.xs[n4 + 3][c] = f2bf(f[it].w);
        }
    }
    __syncthreads();

    f32x4 acc[5][4];
#pragma unroll
    for (int i = 0; i < 5; ++i)
#pragma unroll
        for (int j = 0; j < 4; ++j) acc[i][j] = (f32x4){0.f, 0.f, 0.f, 0.f};

#pragma unroll 2
    for (int k = 0; k < 8; ++k) {
        const int c0 = k * 32;
        bf16x8 wa[5], xb[4];
#pragma unroll
        for (int rs = 0; rs < 5; ++rs)   // swizzled W: 16 B/lane contiguous
            wa[rs] = *(const bf16x8*)&wfrag[(size_t)(((w * 5 + rs) * 8 + k) * 64 + lane) * 8];
#pragma unroll
        for (int ns = 0; ns < 4; ++ns)   // B: n-col = lane&15, k=c=quad*8+j
            xb[ns] = *(const bf16x8*)&sm.xs[ns * 16 + c16][c0 + quad * 8];
#pragma unroll
        for (int rs = 0; rs < 5; ++rs)
#pragma unroll
            for (int ns = 0; ns < 4; ++ns)
                acc[rs][ns] = __builtin_amdgcn_mfma_f32_16x16x32_bf16(
                    wa[rs], xb[ns], acc[rs][ns], 0, 0, 0);
    }

    __syncthreads();   // xs dead; osv may alias it now

    // ---- scatter D + bias into LDS result tiles (bf16)
#pragma unroll
    for (int rs = 0; rs < 5; ++rs) {
#pragma unroll
        for (int r = 0; r < 4; ++r) {
            const int rg = w * 80 + rs * 16 + quad * 4 + r;
            const float bias = (rg < 32) ? bq[rg] : (rg < 64) ? bk[rg - 32] : bv[rg - 64];
#pragma unroll
            for (int ns = 0; ns < 4; ++ns) {
                const int n = ns * 16 + c16;
                const u16 h = f2bf(acc[rs][ns][r] + bias);
                if (rg < 64) sm.osqk[n][rg] = h;
                else         sm.osv[rg - 64][n] = h;
            }
        }
    }
    __syncthreads();

    // ---- coalesced global writes
    {
        u16* dst = (w >= 2) ? kt : qt;
        const int dof = (w >= 2) ? 32 : 0;
        const int wl = w & 1;
        const size_t base = ((size_t)b * NN + n0) * CQ;
#pragma unroll
        for (int it = 0; it < 4; ++it) {
            const int o = wl * 2048 + it * 512 + lane * 8;  // flat in [n][32]
            const int n = o >> 5, d = o & 31;
            const bf16x8 v = *(const bf16x8*)&sm.osqk[n][d + dof];
            *(bf16x8*)&dst[base + o] = v;
        }
    }
#pragma unroll
    for (int it = 0; it < 8; ++it) {
        const int o = it * 2048 + t * 8;                    // flat in [256][64]
        const int c = o >> 6, n = o & 63;
        const bf16x8 v = *(const bf16x8*)&sm.osv[c][n];
        *(bf16x8*)&vv[((size_t)b * CC + c) * NN + n0 + n] = v;
    }
}

// ---------------------------------------------------------------------------
// Kernel 2: flash attention via MFMA (O^T form), no-max softmax, ones-row l.
// m-tile = 32 rows -> grid 1024 (4 blocks/CU, was 2): occupancy was the cap
// (18%, all pipes idle). S work split by (m-strip, n-half) across the 4
// waves (no duplication); each wave still owns a 64-c strip of V/O.
// ps double-buffered -> ONE barrier per step. XCD-swizzled (batch-local L2).
// ---------------------------------------------------------------------------
__global__ __launch_bounds__(256, 4) void attn_kernel(
    const u16* __restrict__ qt, const u16* __restrict__ kt,
    const u16* __restrict__ vv, const float* __restrict__ x,
    const float* __restrict__ gamma_p, float* __restrict__ out)
{
    __shared__ float ps[2][32][68];  // P tile dbuf [m][n-step] f32 (17,408 B)

    // XCD-aware decode: wg->XCD is round-robin on linear id (id%8).
    const int bid  = blockIdx.x;
    const int xcd  = bid & 7;
    const int slot = bid >> 3;                 // 0..127 within XCD
    const int b    = (xcd << 2) | (slot >> 5); // 4 batches per XCD
    const int m0   = (slot & 31) * 32;

    const int t = threadIdx.x, lane = t & 63, w = t >> 6;
    const int quad = lane >> 4, c16 = lane & 15;
    const int sm = w & 1;    // m-strip: rows m0 + sm*16 ..
    const int sh = w >> 1;   // n-half for S: cols sh*32 ..

    // Q A-frag: Q[m=lane&15][d=quad*8+j] for this wave's m-strip
    const bf16x8 qa = *(const bf16x8*)&qt[((size_t)b * NN + m0 + sm * 16 + c16) * CQ + quad * 8];

    bf16x8 ones;
#pragma unroll
    for (int j = 0; j < 8; ++j) ones[j] = (short)0x3F80;   // bf16 1.0

    f32x4 accO[4][2];                // [cs][ms] of O^T: row=c, col=m
    f32x4 lsum[2];                   // l per ms (col = m)
#pragma unroll
    for (int i = 0; i < 2; ++i) {
        lsum[i] = (f32x4){0.f, 0.f, 0.f, 0.f};
#pragma unroll
        for (int cs = 0; cs < 4; ++cs) accO[cs][i] = (f32x4){0.f, 0.f, 0.f, 0.f};
    }

    const u16* vbase = vv + (size_t)b * CC * NN;   // V[c][n]
    const u16* kbase = kt + (size_t)b * NN * CQ;   // K^T[n][d]

    // pre-issue K frags for step 0 (this wave's n-half only)
    bf16x8 kb[2];
#pragma unroll
    for (int s = 0; s < 2; ++s)      // B: n-col = lane&15, k=d=quad*8+j
        kb[s] = *(const bf16x8*)&kbase[(size_t)(sh * 32 + s * 16 + c16) * CQ + quad * 8];

    for (int step = 0; step < 16; ++step) {
        const int nbase = step * 64;
        float* psb = &ps[step & 1][0][0];

        // issue V A-frags for this step (consumed after the barrier;
        // latency hidden by S + exp + barrier)
        bf16x8 va[4][2];
#pragma unroll
        for (int cs = 0; cs < 4; ++cs)
#pragma unroll
            for (int kc = 0; kc < 2; ++kc)   // A: c-row = lane&15, k=n=quad*8+j
                va[cs][kc] = *(const bf16x8*)&vbase[
                    (size_t)(w * 64 + cs * 16 + c16) * NN + nbase + kc * 32 + quad * 8];

        // ---- S strip [16 m][32 n]: wave (sm, sh) owns a unique quadrant ----
        f32x4 accS[2];
#pragma unroll
        for (int s = 0; s < 2; ++s)
            accS[s] = __builtin_amdgcn_mfma_f32_16x16x32_bf16(
                qa, kb[s], (f32x4){0.f, 0.f, 0.f, 0.f}, 0, 0, 0);

        // ---- P = exp(S), unnormalized (|S| <= ~35: safe in fp32) ----
#pragma unroll
        for (int r = 0; r < 4; ++r)
#pragma unroll
            for (int s = 0; s < 2; ++s)
                psb[(sm * 16 + quad * 4 + r) * 68 + sh * 32 + s * 16 + c16] = __expf(accS[s][r]);

        // prefetch K frags for next step
        if (step < 15) {
#pragma unroll
            for (int s = 0; s < 2; ++s)
                kb[s] = *(const bf16x8*)&kbase[(size_t)(nbase + 64 + sh * 32 + s * 16 + c16) * CQ + quad * 8];
        }

        __syncthreads();             // ps[cur] visible to all waves

        // ---- PV: O^T[c][m] += V^T[c][n] · P^T[n][m] ;  l[m] += 1 · P^T ----
#pragma unroll
        for (int ms = 0; ms < 2; ++ms) {
            bf16x8 pb[2];
#pragma unroll
            for (int kc = 0; kc < 2; ++kc) { // B: k=n=quad*8+j, m-col = lane&15
                const f32x4 p0 = *(const f32x4*)&psb[(ms * 16 + c16) * 68 + kc * 32 + quad * 8];
                const f32x4 p1 = *(const f32x4*)&psb[(ms * 16 + c16) * 68 + kc * 32 + quad * 8 + 4];
                bf16x8 pk;
                pk[0] = (short)f2bf(p0[0]); pk[1] = (short)f2bf(p0[1]);
                pk[2] = (short)f2bf(p0[2]); pk[3] = (short)f2bf(p0[3]);
                pk[4] = (short)f2bf(p1[0]); pk[5] = (short)f2bf(p1[1]);
                pk[6] = (short)f2bf(p1[2]); pk[7] = (short)f2bf(p1[3]);
                pb[kc] = pk;
            }
            lsum[ms] = __builtin_amdgcn_mfma_f32_16x16x32_bf16(ones, pb[0], lsum[ms], 0, 0, 0);
            lsum[ms] = __builtin_amdgcn_mfma_f32_16x16x32_bf16(ones, pb[1], lsum[ms], 0, 0, 0);
#pragma unroll
            for (int cs = 0; cs < 4; ++cs) {
#pragma unroll
                for (int kc = 0; kc < 2; ++kc)
                    accO[cs][ms] = __builtin_amdgcn_mfma_f32_16x16x32_bf16(
                        va[cs][kc], pb[kc], accO[cs][ms], 0, 0, 0);
            }
        }
    }

    // ---- epilogue: out = gamma * O / l + x ----
    const float gamma = gamma_p[0];
#pragma unroll
    for (int ms = 0; ms < 2; ++ms) {
        const float inv = gamma / lsum[ms][0];
        const int m = m0 + ms * 16 + c16;
#pragma unroll
        for (int cs = 0; cs < 4; ++cs) {
            const int cbase = w * 64 + cs * 16 + quad * 4;
#pragma unroll
            for (int r = 0; r < 4; ++r) {
                const size_t idx = ((size_t)b * CC + cbase + r) * NN + m;
                out[idx] = accO[cs][ms][r] * inv + x[idx];
            }
        }
    }
}

// ---------------------------------------------------------------------------
extern "C" void kernel_launch(void* const* d_in, const int* in_sizes, int n_in,
                              void* d_out, int out_size, void* d_ws, size_t ws_size,
                              hipStream_t stream)
{
    const float* x  = (const float*)d_in[0];
    const float* Wq = (const float*)d_in[1];
    const float* bq = (const float*)d_in[2];
    const float* Wk = (const float*)d_in[3];
    const float* bk = (const float*)d_in[4];
    const float* Wv = (const float*)d_in[5];
    const float* bv = (const float*)d_in[6];
    const float* gm = (const float*)d_in[7];
    float* out = (float*)d_out;

    // workspace (bf16): qt 2MB | kt 2MB | vv 16MB | wfrag 160KB
    u16* qt    = (u16*)d_ws;
    u16* kt    = qt + (size_t)BB * NN * CQ;
    u16* vv    = kt + (size_t)BB * NN * CQ;
    u16* wfrag = vv + (size_t)BB * CC * NN;

    wpack_kernel<<<320, 256, 0, stream>>>(Wq, Wk, Wv, wfrag);
    dim3 grid(16, BB);
    qkv_kernel<<<grid, 256, 0, stream>>>(x, wfrag, bq, bk, bv, qt, kt, vv);
    attn_kernel<<<1024, 256, 0, stream>>>(qt, kt, vv, x, gm, out);
}

// Round 2
// 155.942 us; speedup vs baseline: 1.1650x; 1.1650x over previous
//
#include <hip/hip_runtime.h>
#include <math.h>

#define BB 32
#define CC 256
#define CQ 32      // C/8
#define NN 1024    // H*W

typedef short bf16x8 __attribute__((ext_vector_type(8)));
typedef float f32x4  __attribute__((ext_vector_type(4)));
typedef unsigned short u16;

// fp32 -> bf16 RNE
__device__ __forceinline__ u16 f2bf(float f) {
    unsigned u = __float_as_uint(f);
    u = (u + 0x7FFFu + ((u >> 16) & 1u)) >> 16;
    return (u16)u;
}

// ---------------------------------------------------------------------------
// Kernel 0: pack fused W = [Wq(32); Wk(32); Wv(256)] into MFMA A-frag order:
// wfrag[((rt*8 + kc)*64 + lane)*8 + j] = W[rt*16 + (lane&15)][kc*32 + (lane>>4)*8 + j]
// ---------------------------------------------------------------------------
__global__ void wpack_kernel(const float* __restrict__ Wq,
                             const float* __restrict__ Wk,
                             const float* __restrict__ Wv,
                             u16* __restrict__ wfrag)
{
    const int o = blockIdx.x * 256 + threadIdx.x;     // 0 .. 81919
    const int j    = o & 7;
    const int lane = (o >> 3) & 63;
    const int kc   = (o >> 9) & 7;
    const int rt   = o >> 12;                         // 0..19
    const int row  = rt * 16 + (lane & 15);
    const int col  = kc * 32 + (lane >> 4) * 8 + j;
    const float v = (row < 32) ? Wq[row * 256 + col]
                  : (row < 64) ? Wk[(row - 32) * 256 + col]
                               : Wv[(row - 64) * 256 + col];
    wfrag[o] = f2bf(v);
}

// ---------------------------------------------------------------------------
// Kernel 1: QKV projection via MFMA. grid(16 n-tiles, 32 b), 256 thr.
// Staging transpose was 32-way bank-conflicted (n=4*(t&15), stride 272 u16
// == 0 mod 32 dw). Fix: stride 268 u16 (134 dw == 6 mod 32) + float2 loads
// (n=2*(t&31)) -> ~2-4-way writes; frag reads as two 8B-aligned short4.
// ---------------------------------------------------------------------------
struct QSmem {
    union {
        u16 xs[64][268];     // x^T tile [n][c] bf16, stride 268 (conflict fix)
        u16 osv[CC][72];     // v result [c][n]
    };
    u16 osqk[64][72];        // q|k result [n][d], d 0..31 = q, 32..63 = k
};

__global__ __launch_bounds__(256, 2) void qkv_kernel(
    const float* __restrict__ x, const u16* __restrict__ wfrag,
    const float* __restrict__ bq, const float* __restrict__ bk,
    const float* __restrict__ bv,
    u16* __restrict__ qt, u16* __restrict__ kt, u16* __restrict__ vv)
{
    __shared__ QSmem sm;
    const int b = blockIdx.y, n0 = blockIdx.x * 64;
    const int t = threadIdx.x;
    const int lane = t & 63, w = t >> 6;
    const int quad = lane >> 4, c16 = lane & 15;

    // ---- stage x^T bf16: float2 loads (coalesced, 2 rows/wave-inst)
    {
        const float* xb = x + (size_t)b * CC * NN + n0;
        const int n2 = 2 * (lane & 31);       // 0..62
        const int cr = w * 2 + (lane >> 5);   // 0..7 within each round of 8 c
        float2 f[32];
#pragma unroll
        for (int it = 0; it < 32; ++it)
            f[it] = *(const float2*)(xb + (size_t)(it * 8 + cr) * NN + n2);
#pragma unroll
        for (int it = 0; it < 32; ++it) {
            const int c = it * 8 + cr;
            sm.xs[n2 + 0][c] = f2bf(f[it].x);
            sm.xs[n2 + 1][c] = f2bf(f[it].y);
        }
    }
    __syncthreads();

    f32x4 acc[5][4];
#pragma unroll
    for (int i = 0; i < 5; ++i)
#pragma unroll
        for (int j = 0; j < 4; ++j) acc[i][j] = (f32x4){0.f, 0.f, 0.f, 0.f};

#pragma unroll 2
    for (int k = 0; k < 8; ++k) {
        const int c0 = k * 32;
        bf16x8 wa[5], xb[4];
#pragma unroll
        for (int rs = 0; rs < 5; ++rs)   // swizzled W: 16 B/lane contiguous
            wa[rs] = *(const bf16x8*)&wfrag[(size_t)(((w * 5 + rs) * 8 + k) * 64 + lane) * 8];
#pragma unroll
        for (int ns = 0; ns < 4; ++ns) { // B: n-col = lane&15, k=c=quad*8+j
            const short4 a = *(const short4*)&sm.xs[ns * 16 + c16][c0 + quad * 8];
            const short4 b2 = *(const short4*)&sm.xs[ns * 16 + c16][c0 + quad * 8 + 4];
            bf16x8 v;
            v[0] = a.x; v[1] = a.y; v[2] = a.z; v[3] = a.w;
            v[4] = b2.x; v[5] = b2.y; v[6] = b2.z; v[7] = b2.w;
            xb[ns] = v;
        }
#pragma unroll
        for (int rs = 0; rs < 5; ++rs)
#pragma unroll
            for (int ns = 0; ns < 4; ++ns)
                acc[rs][ns] = __builtin_amdgcn_mfma_f32_16x16x32_bf16(
                    wa[rs], xb[ns], acc[rs][ns], 0, 0, 0);
    }

    __syncthreads();   // xs dead; osv may alias it now

    // ---- scatter D + bias into LDS result tiles (bf16)
#pragma unroll
    for (int rs = 0; rs < 5; ++rs) {
#pragma unroll
        for (int r = 0; r < 4; ++r) {
            const int rg = w * 80 + rs * 16 + quad * 4 + r;
            const float bias = (rg < 32) ? bq[rg] : (rg < 64) ? bk[rg - 32] : bv[rg - 64];
#pragma unroll
            for (int ns = 0; ns < 4; ++ns) {
                const int n = ns * 16 + c16;
                const u16 h = f2bf(acc[rs][ns][r] + bias);
                if (rg < 64) sm.osqk[n][rg] = h;
                else         sm.osv[rg - 64][n] = h;
            }
        }
    }
    __syncthreads();

    // ---- coalesced global writes
    {
        u16* dst = (w >= 2) ? kt : qt;
        const int dof = (w >= 2) ? 32 : 0;
        const int wl = w & 1;
        const size_t base = ((size_t)b * NN + n0) * CQ;
#pragma unroll
        for (int it = 0; it < 4; ++it) {
            const int o = wl * 2048 + it * 512 + lane * 8;  // flat in [n][32]
            const int n = o >> 5, d = o & 31;
            const bf16x8 v = *(const bf16x8*)&sm.osqk[n][d + dof];
            *(bf16x8*)&dst[base + o] = v;
        }
    }
#pragma unroll
    for (int it = 0; it < 8; ++it) {
        const int o = it * 2048 + t * 8;                    // flat in [256][64]
        const int c = o >> 6, n = o & 63;
        const bf16x8 v = *(const bf16x8*)&sm.osv[c][n];
        *(bf16x8*)&vv[((size_t)b * CC + c) * NN + n0 + n] = v;
    }
}

// ---------------------------------------------------------------------------
// Kernel 2: flash attention, m64 geometry (round-0: occupancy is NOT the
// lever; per-wave ILP is). Changes vs round-0:
//  - P stored in LDS as bf16 in B-frag order (convert at write: 16 f2bf,
//    not 64 at read). XOR block-swizzle nblk^=(m>>2)&3 -> both the b16
//    writes and b128 reads are bank-conflict-free. ps halves to 18 KB.
//  - V frags double-buffered one FULL step ahead (issued post-barrier,
//    consumed next step) -> L2 latency fully covered. VGPR ~210 is free:
//    grid 512 = 2 blocks/CU regardless; lb(256,2) keeps cap at 256.
// ---------------------------------------------------------------------------
__global__ __launch_bounds__(256, 2) void attn_kernel(
    const u16* __restrict__ qt, const u16* __restrict__ kt,
    const u16* __restrict__ vv, const float* __restrict__ x,
    const float* __restrict__ gamma_p, float* __restrict__ out)
{
    __shared__ u16 ps16[2][64][72];  // P dbuf, bf16, swizzled (18,432 B)

    // XCD-aware decode: wg->XCD is round-robin on linear id (id%8).
    const int bid  = blockIdx.x;
    const int xcd  = bid & 7;
    const int slot = bid >> 3;                 // 0..63 within XCD
    const int b    = (xcd << 2) | (slot >> 4); // 4 batches per XCD
    const int m0   = (slot & 15) * 64;

    const int t = threadIdx.x, lane = t & 63, w = t >> 6;
    const int quad = lane >> 4, c16 = lane & 15;
    const int ch   = c16 >> 3;        // write-side n-block low bit
    const int c7   = c16 & 7;
    const int qkey = (c16 >> 2) & 3;  // read-side swizzle key

    // Q A-frag: Q[m=lane&15][d=quad*8+j]
    const bf16x8 qa = *(const bf16x8*)&qt[((size_t)b * NN + m0 + w * 16 + c16) * CQ + quad * 8];

    bf16x8 ones;
#pragma unroll
    for (int j = 0; j < 8; ++j) ones[j] = (short)0x3F80;   // bf16 1.0

    f32x4 accO[4][4];                // [cs][ms] of O^T: row=c, col=m
    f32x4 lsum[4];                   // l per ms (col = m)
#pragma unroll
    for (int i = 0; i < 4; ++i) {
        lsum[i] = (f32x4){0.f, 0.f, 0.f, 0.f};
#pragma unroll
        for (int j = 0; j < 4; ++j) accO[i][j] = (f32x4){0.f, 0.f, 0.f, 0.f};
    }

    const u16* vbase = vv + (size_t)b * CC * NN;   // V[c][n]
    const u16* kbase = kt + (size_t)b * NN * CQ;   // K^T[n][d]

    // pre-issue K frags for step 0
    bf16x8 kb[4];
#pragma unroll
    for (int s = 0; s < 4; ++s)      // B: n-col = lane&15, k=d=quad*8+j
        kb[s] = *(const bf16x8*)&kbase[(size_t)(s * 16 + c16) * CQ + quad * 8];

    // pre-issue V frags for step 0
    bf16x8 vaA[4][2], vaB[4][2];
#pragma unroll
    for (int cs = 0; cs < 4; ++cs)
#pragma unroll
        for (int kc = 0; kc < 2; ++kc)   // A: c-row = lane&15, k=n=quad*8+j
            vaA[cs][kc] = *(const bf16x8*)&vbase[
                (size_t)(w * 64 + cs * 16 + c16) * NN + kc * 32 + quad * 8];

    auto STEP = [&](int step, bf16x8 (&vc)[4][2], bf16x8 (&vn)[4][2]) {
        const int nbase = step * 64;
        u16* psb = &ps16[step & 1][0][0];

        // ---- S = Q·K^T strip [16 m][64 n] ----
        f32x4 accS[4];
#pragma unroll
        for (int s = 0; s < 4; ++s)
            accS[s] = __builtin_amdgcn_mfma_f32_16x16x32_bf16(
                qa, kb[s], (f32x4){0.f, 0.f, 0.f, 0.f}, 0, 0, 0);

        // ---- P = exp(S) -> bf16, swizzled store (conflict-free b16) ----
        const int rowb = w * 16 + quad * 4;
#pragma unroll
        for (int r = 0; r < 4; ++r)
#pragma unroll
            for (int s = 0; s < 4; ++s) {
                const int nb = (2 * s + ch) ^ quad;
                psb[(rowb + r) * 72 + nb * 8 + c7] = f2bf(__expf(accS[s][r]));
            }

        // prefetch K frags for next step
        if (step < 15) {
#pragma unroll
            for (int s = 0; s < 4; ++s)
                kb[s] = *(const bf16x8*)&kbase[(size_t)(nbase + 64 + s * 16 + c16) * CQ + quad * 8];
        }

        __syncthreads();             // ps[cur] visible to all waves

        // issue V frags for step+1 (consumed next step: full-step latency cover)
        if (step < 15) {
#pragma unroll
            for (int cs = 0; cs < 4; ++cs)
#pragma unroll
                for (int kc = 0; kc < 2; ++kc)
                    vn[cs][kc] = *(const bf16x8*)&vbase[
                        (size_t)(w * 64 + cs * 16 + c16) * NN + nbase + 64 + kc * 32 + quad * 8];
        }

        // ---- PV: O^T[c][m] += V^T[c][n] · P^T[n][m] ;  l[m] += 1 · P^T ----
#pragma unroll
        for (int ms = 0; ms < 4; ++ms) {
            bf16x8 pb[2];
#pragma unroll
            for (int kc = 0; kc < 2; ++kc)   // direct b128, swizzled addr
                pb[kc] = *(const bf16x8*)&psb[(ms * 16 + c16) * 72
                                              + (4 * kc + (quad ^ qkey)) * 8];
            lsum[ms] = __builtin_amdgcn_mfma_f32_16x16x32_bf16(ones, pb[0], lsum[ms], 0, 0, 0);
            lsum[ms] = __builtin_amdgcn_mfma_f32_16x16x32_bf16(ones, pb[1], lsum[ms], 0, 0, 0);
#pragma unroll
            for (int cs = 0; cs < 4; ++cs) {
#pragma unroll
                for (int kc = 0; kc < 2; ++kc)
                    accO[cs][ms] = __builtin_amdgcn_mfma_f32_16x16x32_bf16(
                        vc[cs][kc], pb[kc], accO[cs][ms], 0, 0, 0);
            }
        }
    };

    for (int it = 0; it < 8; ++it) {      // static 2x unroll: vaA/vaB swap
        STEP(2 * it,     vaA, vaB);
        STEP(2 * it + 1, vaB, vaA);
    }

    // ---- epilogue: out = gamma * O / l + x ----
    const float gamma = gamma_p[0];
#pragma unroll
    for (int ms = 0; ms < 4; ++ms) {
        const float inv = gamma / lsum[ms][0];
        const int m = m0 + ms * 16 + c16;
#pragma unroll
        for (int cs = 0; cs < 4; ++cs) {
            const int cbase = w * 64 + cs * 16 + quad * 4;
#pragma unroll
            for (int r = 0; r < 4; ++r) {
                const size_t idx = ((size_t)b * CC + cbase + r) * NN + m;
                out[idx] = accO[cs][ms][r] * inv + x[idx];
            }
        }
    }
}

// ---------------------------------------------------------------------------
extern "C" void kernel_launch(void* const* d_in, const int* in_sizes, int n_in,
                              void* d_out, int out_size, void* d_ws, size_t ws_size,
                              hipStream_t stream)
{
    const float* x  = (const float*)d_in[0];
    const float* Wq = (const float*)d_in[1];
    const float* bq = (const float*)d_in[2];
    const float* Wk = (const float*)d_in[3];
    const float* bk = (const float*)d_in[4];
    const float* Wv = (const float*)d_in[5];
    const float* bv = (const float*)d_in[6];
    const float* gm = (const float*)d_in[7];
    float* out = (float*)d_out;

    // workspace (bf16): qt 2MB | kt 2MB | vv 16MB | wfrag 160KB
    u16* qt    = (u16*)d_ws;
    u16* kt    = qt + (size_t)BB * NN * CQ;
    u16* vv    = kt + (size_t)BB * NN * CQ;
    u16* wfrag = vv + (size_t)BB * CC * NN;

    wpack_kernel<<<320, 256, 0, stream>>>(Wq, Wk, Wv, wfrag);
    dim3 grid(16, BB);
    qkv_kernel<<<grid, 256, 0, stream>>>(x, wfrag, bq, bk, bv, qt, kt, vv);
    attn_kernel<<<512, 256, 0, stream>>>(qt, kt, vv, x, gm, out);
}

// Round 3
// 152.895 us; speedup vs baseline: 1.1883x; 1.0199x over previous
//
#include <hip/hip_runtime.h>
#include <math.h>

#define BB 32
#define CC 256
#define CQ 32      // C/8
#define NN 1024    // H*W

typedef short bf16x8 __attribute__((ext_vector_type(8)));
typedef float f32x4  __attribute__((ext_vector_type(4)));
typedef unsigned short u16;

// fp32 -> bf16 RNE
__device__ __forceinline__ u16 f2bf(float f) {
    unsigned u = __float_as_uint(f);
    u = (u + 0x7FFFu + ((u >> 16) & 1u)) >> 16;
    return (u16)u;
}

// pack two fp32 -> two bf16 in one u32 (single VALU op)
__device__ __forceinline__ unsigned cvt_pk_bf16(float lo, float hi) {
    unsigned r;
    asm("v_cvt_pk_bf16_f32 %0, %1, %2" : "=v"(r) : "v"(lo), "v"(hi));
    return r;
}

// ---------------------------------------------------------------------------
// Kernel 0: pack fused W = [Wq(32); Wk(32); Wv(256)] into MFMA A-frag order:
// wfrag[((rt*8 + kc)*64 + lane)*8 + j] = W[rt*16 + (lane&15)][kc*32 + (lane>>4)*8 + j]
// ---------------------------------------------------------------------------
__global__ void wpack_kernel(const float* __restrict__ Wq,
                             const float* __restrict__ Wk,
                             const float* __restrict__ Wv,
                             u16* __restrict__ wfrag)
{
    const int o = blockIdx.x * 256 + threadIdx.x;     // 0 .. 81919
    const int j    = o & 7;
    const int lane = (o >> 3) & 63;
    const int kc   = (o >> 9) & 7;
    const int rt   = o >> 12;                         // 0..19
    const int row  = rt * 16 + (lane & 15);
    const int col  = kc * 32 + (lane >> 4) * 8 + j;
    const float v = (row < 32) ? Wq[row * 256 + col]
                  : (row < 64) ? Wk[(row - 32) * 256 + col]
                               : Wv[(row - 64) * 256 + col];
    wfrag[o] = f2bf(v);
}

// ---------------------------------------------------------------------------
// Kernel 1: QKV projection via MFMA. grid(16 n-tiles, 32 b), 256 thr.
// (unchanged this round: non-attn time is within +-3us noise across the
// rounds that edited it; no counters available to target it yet)
// ---------------------------------------------------------------------------
struct QSmem {
    union {
        u16 xs[64][268];     // x^T tile [n][c] bf16, stride 268
        u16 osv[CC][72];     // v result [c][n]
    };
    u16 osqk[64][72];        // q|k result [n][d], d 0..31 = q, 32..63 = k
};

__global__ __launch_bounds__(256, 2) void qkv_kernel(
    const float* __restrict__ x, const u16* __restrict__ wfrag,
    const float* __restrict__ bq, const float* __restrict__ bk,
    const float* __restrict__ bv,
    u16* __restrict__ qt, u16* __restrict__ kt, u16* __restrict__ vv)
{
    __shared__ QSmem sm;
    const int b = blockIdx.y, n0 = blockIdx.x * 64;
    const int t = threadIdx.x;
    const int lane = t & 63, w = t >> 6;
    const int quad = lane >> 4, c16 = lane & 15;

    // ---- stage x^T bf16: float2 loads (coalesced, 2 rows/wave-inst)
    {
        const float* xb = x + (size_t)b * CC * NN + n0;
        const int n2 = 2 * (lane & 31);       // 0..62
        const int cr = w * 2 + (lane >> 5);   // 0..7 within each round of 8 c
        float2 f[32];
#pragma unroll
        for (int it = 0; it < 32; ++it)
            f[it] = *(const float2*)(xb + (size_t)(it * 8 + cr) * NN + n2);
#pragma unroll
        for (int it = 0; it < 32; ++it) {
            const int c = it * 8 + cr;
            sm.xs[n2 + 0][c] = f2bf(f[it].x);
            sm.xs[n2 + 1][c] = f2bf(f[it].y);
        }
    }
    __syncthreads();

    f32x4 acc[5][4];
#pragma unroll
    for (int i = 0; i < 5; ++i)
#pragma unroll
        for (int j = 0; j < 4; ++j) acc[i][j] = (f32x4){0.f, 0.f, 0.f, 0.f};

#pragma unroll 2
    for (int k = 0; k < 8; ++k) {
        const int c0 = k * 32;
        bf16x8 wa[5], xb[4];
#pragma unroll
        for (int rs = 0; rs < 5; ++rs)   // swizzled W: 16 B/lane contiguous
            wa[rs] = *(const bf16x8*)&wfrag[(size_t)(((w * 5 + rs) * 8 + k) * 64 + lane) * 8];
#pragma unroll
        for (int ns = 0; ns < 4; ++ns) { // B: n-col = lane&15, k=c=quad*8+j
            const short4 a = *(const short4*)&sm.xs[ns * 16 + c16][c0 + quad * 8];
            const short4 b2 = *(const short4*)&sm.xs[ns * 16 + c16][c0 + quad * 8 + 4];
            bf16x8 v;
            v[0] = a.x; v[1] = a.y; v[2] = a.z; v[3] = a.w;
            v[4] = b2.x; v[5] = b2.y; v[6] = b2.z; v[7] = b2.w;
            xb[ns] = v;
        }
#pragma unroll
        for (int rs = 0; rs < 5; ++rs)
#pragma unroll
            for (int ns = 0; ns < 4; ++ns)
                acc[rs][ns] = __builtin_amdgcn_mfma_f32_16x16x32_bf16(
                    wa[rs], xb[ns], acc[rs][ns], 0, 0, 0);
    }

    __syncthreads();   // xs dead; osv may alias it now

    // ---- scatter D + bias into LDS result tiles (bf16)
#pragma unroll
    for (int rs = 0; rs < 5; ++rs) {
#pragma unroll
        for (int r = 0; r < 4; ++r) {
            const int rg = w * 80 + rs * 16 + quad * 4 + r;
            const float bias = (rg < 32) ? bq[rg] : (rg < 64) ? bk[rg - 32] : bv[rg - 64];
#pragma unroll
            for (int ns = 0; ns < 4; ++ns) {
                const int n = ns * 16 + c16;
                const u16 h = f2bf(acc[rs][ns][r] + bias);
                if (rg < 64) sm.osqk[n][rg] = h;
                else         sm.osv[rg - 64][n] = h;
            }
        }
    }
    __syncthreads();

    // ---- coalesced global writes
    {
        u16* dst = (w >= 2) ? kt : qt;
        const int dof = (w >= 2) ? 32 : 0;
        const int wl = w & 1;
        const size_t base = ((size_t)b * NN + n0) * CQ;
#pragma unroll
        for (int it = 0; it < 4; ++it) {
            const int o = wl * 2048 + it * 512 + lane * 8;  // flat in [n][32]
            const int n = o >> 5, d = o & 31;
            const bf16x8 v = *(const bf16x8*)&sm.osqk[n][d + dof];
            *(bf16x8*)&dst[base + o] = v;
        }
    }
#pragma unroll
    for (int it = 0; it < 8; ++it) {
        const int o = it * 2048 + t * 8;                    // flat in [256][64]
        const int c = o >> 6, n = o & 63;
        const bf16x8 v = *(const bf16x8*)&sm.osv[c][n];
        *(bf16x8*)&vv[((size_t)b * CC + c) * NN + n0 + n] = v;
    }
}

// ---------------------------------------------------------------------------
// Kernel 2: flash attention, m64 block / 8 waves (512 thr).
// r2 post-mortem: VALU-diet + conflict fix were NULL on time -> kernel is
// latency-bound at 2 waves/SIMD (grid 512 x 4-wave blocks = 8 waves/CU).
// Fix: same m64 tile, 8 waves -> per-wave state halves (VGPR ~118 < 128),
// 2 blocks/CU now = 16 waves/CU = 4 waves/SIMD. S split (sm,sh) across
// waves (no duplication); lsum de-duplicated (each wave owns ms0=w&3,
// shared via LDS at end). P path: v_cvt_pk_bf16_f32 + swizzled b16 stores
// (conflict-free, same mapping as r2). One barrier/step, ps dbuf.
// ---------------------------------------------------------------------------
__global__ __launch_bounds__(512, 4) void attn_kernel(
    const u16* __restrict__ qt, const u16* __restrict__ kt,
    const u16* __restrict__ vv, const float* __restrict__ x,
    const float* __restrict__ gamma_p, float* __restrict__ out)
{
    __shared__ u16 ps16[2][64][72];  // P dbuf, bf16, swizzled (18,432 B)
    __shared__ float lsh[64];        // shared l[m]

    // XCD-aware decode: wg->XCD is round-robin on linear id (id%8).
    const int bid  = blockIdx.x;
    const int xcd  = bid & 7;
    const int slot = bid >> 3;                 // 0..63 within XCD
    const int b    = (xcd << 2) | (slot >> 4); // 4 batches per XCD
    const int m0   = (slot & 15) * 64;

    const int t = threadIdx.x, lane = t & 63, w = t >> 6;  // w 0..7
    const int quad = lane >> 4, c16 = lane & 15;
    const int ch   = c16 >> 3;        // write-side n-block low bit
    const int c7   = c16 & 7;
    const int qkey = (c16 >> 2) & 3;  // read-side swizzle key
    const int sm   = w & 3;           // S m-strip (16 rows)
    const int sh   = w >> 2;          // S n-half (32 cols)
    const int ms0  = w & 3;           // lsum ownership

    // Q A-frag for this wave's S m-strip: Q[m=lane&15][d=quad*8+j]
    const bf16x8 qa = *(const bf16x8*)&qt[((size_t)b * NN + m0 + sm * 16 + c16) * CQ + quad * 8];

    bf16x8 ones;
#pragma unroll
    for (int j = 0; j < 8; ++j) ones[j] = (short)0x3F80;   // bf16 1.0

    f32x4 accO[2][4];                // [cs][ms] of O^T: row=c (c32 strip), col=m
    f32x4 lsum = (f32x4){0.f, 0.f, 0.f, 0.f};   // l for ms0 only
#pragma unroll
    for (int cs = 0; cs < 2; ++cs)
#pragma unroll
        for (int j = 0; j < 4; ++j) accO[cs][j] = (f32x4){0.f, 0.f, 0.f, 0.f};

    const u16* vbase = vv + (size_t)b * CC * NN;   // V[c][n]
    const u16* kbase = kt + (size_t)b * NN * CQ;   // K^T[n][d]

    // pre-issue K frags for step 0 (this wave's n-half)
    bf16x8 kb[2];
#pragma unroll
    for (int s = 0; s < 2; ++s)      // B: n-col = lane&15, k=d=quad*8+j
        kb[s] = *(const bf16x8*)&kbase[(size_t)(sh * 32 + s * 16 + c16) * CQ + quad * 8];

    for (int step = 0; step < 16; ++step) {
        const int nbase = step * 64;
        u16* psb = &ps16[step & 1][0][0];

        // V A-frags for this step (c32 strip; consumed post-barrier:
        // S + exp + barrier wait covers the L2 latency)
        bf16x8 va[2][2];
#pragma unroll
        for (int cs = 0; cs < 2; ++cs)
#pragma unroll
            for (int kc = 0; kc < 2; ++kc)   // A: c-row = lane&15, k=n=quad*8+j
                va[cs][kc] = *(const bf16x8*)&vbase[
                    (size_t)(w * 32 + cs * 16 + c16) * NN + nbase + kc * 32 + quad * 8];

        // ---- S strip [16 m][32 n]: wave (sm, sh) owns a unique piece ----
        f32x4 accS[2];
#pragma unroll
        for (int s = 0; s < 2; ++s)
            accS[s] = __builtin_amdgcn_mfma_f32_16x16x32_bf16(
                qa, kb[s], (f32x4){0.f, 0.f, 0.f, 0.f}, 0, 0, 0);

        // ---- P = exp(S) -> bf16 via cvt_pk, swizzled b16 stores ----
        const int rowb = sm * 16 + quad * 4;
#pragma unroll
        for (int s = 0; s < 2; ++s) {
            const int nb = (sh * 4 + 2 * s + ch) ^ quad;
            u16* pw = &psb[rowb * 72 + nb * 8 + c7];
            const float e0 = __expf(accS[s][0]);
            const float e1 = __expf(accS[s][1]);
            const float e2 = __expf(accS[s][2]);
            const float e3 = __expf(accS[s][3]);
            const unsigned p01 = cvt_pk_bf16(e0, e1);
            const unsigned p23 = cvt_pk_bf16(e2, e3);
            pw[0]       = (u16)p01;
            pw[72]      = (u16)(p01 >> 16);
            pw[144]     = (u16)p23;
            pw[216]     = (u16)(p23 >> 16);
        }

        // prefetch K frags for next step
        if (step < 15) {
#pragma unroll
            for (int s = 0; s < 2; ++s)
                kb[s] = *(const bf16x8*)&kbase[
                    (size_t)(nbase + 64 + sh * 32 + s * 16 + c16) * CQ + quad * 8];
        }

        __syncthreads();             // ps[cur] visible to all waves

        // ---- PV: O^T[c][m] += V^T[c][n] · P^T[n][m] ; l[ms0] += 1 · P^T ----
#pragma unroll
        for (int msi = 0; msi < 4; ++msi) {
            bf16x8 pb[2];
#pragma unroll
            for (int kc = 0; kc < 2; ++kc)   // direct b128, swizzled addr
                pb[kc] = *(const bf16x8*)&psb[(msi * 16 + c16) * 72
                                              + (4 * kc + (quad ^ qkey)) * 8];
            if (msi == ms0) {
                lsum = __builtin_amdgcn_mfma_f32_16x16x32_bf16(ones, pb[0], lsum, 0, 0, 0);
                lsum = __builtin_amdgcn_mfma_f32_16x16x32_bf16(ones, pb[1], lsum, 0, 0, 0);
            }
#pragma unroll
            for (int cs = 0; cs < 2; ++cs)
#pragma unroll
                for (int kc = 0; kc < 2; ++kc)
                    accO[cs][msi] = __builtin_amdgcn_mfma_f32_16x16x32_bf16(
                        va[cs][kc], pb[kc], accO[cs][msi], 0, 0, 0);
        }
    }

    // ---- share l[m] (each ms owned by waves w&3==ms; w<4 writes) ----
    if (sh == 0 && quad == 0) lsh[ms0 * 16 + c16] = lsum[0];
    __syncthreads();

    // ---- epilogue: out = gamma * O / l + x ----
    const float gamma = gamma_p[0];
#pragma unroll
    for (int ms = 0; ms < 4; ++ms) {
        const float inv = gamma / lsh[ms * 16 + c16];
        const int m = m0 + ms * 16 + c16;
#pragma unroll
        for (int cs = 0; cs < 2; ++cs) {
            const int cbase = w * 32 + cs * 16 + quad * 4;
#pragma unroll
            for (int r = 0; r < 4; ++r) {
                const size_t idx = ((size_t)b * CC + cbase + r) * NN + m;
                out[idx] = accO[cs][ms][r] * inv + x[idx];
            }
        }
    }
}

// ---------------------------------------------------------------------------
extern "C" void kernel_launch(void* const* d_in, const int* in_sizes, int n_in,
                              void* d_out, int out_size, void* d_ws, size_t ws_size,
                              hipStream_t stream)
{
    const float* x  = (const float*)d_in[0];
    const float* Wq = (const float*)d_in[1];
    const float* bq = (const float*)d_in[2];
    const float* Wk = (const float*)d_in[3];
    const float* bk = (const float*)d_in[4];
    const float* Wv = (const float*)d_in[5];
    const float* bv = (const float*)d_in[6];
    const float* gm = (const float*)d_in[7];
    float* out = (float*)d_out;

    // workspace (bf16): qt 2MB | kt 2MB | vv 16MB | wfrag 160KB
    u16* qt    = (u16*)d_ws;
    u16* kt    = qt + (size_t)BB * NN * CQ;
    u16* vv    = kt + (size_t)BB * NN * CQ;
    u16* wfrag = vv + (size_t)BB * CC * NN;

    wpack_kernel<<<320, 256, 0, stream>>>(Wq, Wk, Wv, wfrag);
    dim3 grid(16, BB);
    qkv_kernel<<<grid, 256, 0, stream>>>(x, wfrag, bq, bk, bv, qt, kt, vv);
    attn_kernel<<<512, 512, 0, stream>>>(qt, kt, vv, x, gm, out);
}

// Round 4
// 150.878 us; speedup vs baseline: 1.2041x; 1.0134x over previous
//
#include <hip/hip_runtime.h>
#include <math.h>

#define BB 32
#define CC 256
#define CQ 32      // C/8
#define NN 1024    // H*W

typedef short bf16x8 __attribute__((ext_vector_type(8)));
typedef float f32x4  __attribute__((ext_vector_type(4)));
typedef unsigned short u16;

// fp32 -> bf16 RNE
__device__ __forceinline__ u16 f2bf(float f) {
    unsigned u = __float_as_uint(f);
    u = (u + 0x7FFFu + ((u >> 16) & 1u)) >> 16;
    return (u16)u;
}

// pack two fp32 -> two bf16 in one u32 (single VALU op)
__device__ __forceinline__ unsigned cvt_pk_bf16(float lo, float hi) {
    unsigned r;
    asm("v_cvt_pk_bf16_f32 %0, %1, %2" : "=v"(r) : "v"(lo), "v"(hi));
    return r;
}

// ---------------------------------------------------------------------------
// Kernel 0: pack fused W = [Wq(32); Wk(32); Wv(256)] into MFMA A-frag order:
// wfrag[((rt*8 + kc)*64 + lane)*8 + j] = W[rt*16 + (lane&15)][kc*32 + (lane>>4)*8 + j]
// ---------------------------------------------------------------------------
__global__ void wpack_kernel(const float* __restrict__ Wq,
                             const float* __restrict__ Wk,
                             const float* __restrict__ Wv,
                             u16* __restrict__ wfrag)
{
    const int o = blockIdx.x * 256 + threadIdx.x;     // 0 .. 81919
    const int j    = o & 7;
    const int lane = (o >> 3) & 63;
    const int kc   = (o >> 9) & 7;
    const int rt   = o >> 12;                         // 0..19
    const int row  = rt * 16 + (lane & 15);
    const int col  = kc * 32 + (lane >> 4) * 8 + j;
    const float v = (row < 32) ? Wq[row * 256 + col]
                  : (row < 64) ? Wk[(row - 32) * 256 + col]
                               : Wv[(row - 64) * 256 + col];
    wfrag[o] = f2bf(v);
}

// ---------------------------------------------------------------------------
// Kernel 1: QKV projection. Deduced qkv ~45-50us (total-minus-attn residue,
// stable across 4 rounds) vs ~9us roofline -> latency-bound at 2 waves/SIMD.
// Fix: n-tile 64->32, grid (32,32)=1024 blocks = 4 blocks/CU = 16 waves/CU;
// per-thread staging queue halves (8 float4). ~115 VGPR fits lb(256,4).
// ---------------------------------------------------------------------------
struct QSmem {
    union {
        u16 xs[32][268];     // x^T tile [n][c] bf16, stride 268 (bank-spread)
        u16 osv[CC][40];     // v result [c][n]
    };
    u16 osqk[32][72];        // q|k result [n][d], d 0..31 = q, 32..63 = k
};

__global__ __launch_bounds__(256, 4) void qkv_kernel(
    const float* __restrict__ x, const u16* __restrict__ wfrag,
    const float* __restrict__ bq, const float* __restrict__ bk,
    const float* __restrict__ bv,
    u16* __restrict__ qt, u16* __restrict__ kt, u16* __restrict__ vv)
{
    __shared__ QSmem sm;
    const int b = blockIdx.y, n0 = blockIdx.x * 32;
    const int t = threadIdx.x;
    const int lane = t & 63, w = t >> 6;
    const int quad = lane >> 4, c16 = lane & 15;

    // ---- stage x^T bf16: 8 coalesced float4 loads, transpose-pack
    {
        const float* xb = x + (size_t)b * CC * NN + n0;
        const int n4 = (t & 7) * 4;       // n quad 0..28
        const int cr = t >> 3;            // 0..31: c within group of 32
        float4 f[8];
#pragma unroll
        for (int it = 0; it < 8; ++it)
            f[it] = *(const float4*)(xb + (size_t)(it * 32 + cr) * NN + n4);
#pragma unroll
        for (int it = 0; it < 8; ++it) {
            const int c = it * 32 + cr;
            sm.xs[n4 + 0][c] = f2bf(f[it].x);
            sm.xs[n4 + 1][c] = f2bf(f[it].y);
            sm.xs[n4 + 2][c] = f2bf(f[it].z);
            sm.xs[n4 + 3][c] = f2bf(f[it].w);
        }
    }
    __syncthreads();

    f32x4 acc[5][2];
#pragma unroll
    for (int i = 0; i < 5; ++i)
#pragma unroll
        for (int j = 0; j < 2; ++j) acc[i][j] = (f32x4){0.f, 0.f, 0.f, 0.f};

#pragma unroll 2
    for (int k = 0; k < 8; ++k) {
        const int c0 = k * 32;
        bf16x8 wa[5], xb[2];
#pragma unroll
        for (int rs = 0; rs < 5; ++rs)   // swizzled W: 16 B/lane contiguous
            wa[rs] = *(const bf16x8*)&wfrag[(size_t)(((w * 5 + rs) * 8 + k) * 64 + lane) * 8];
#pragma unroll
        for (int ns = 0; ns < 2; ++ns) { // B: n-col = lane&15, k=c=quad*8+j
            const short4 a = *(const short4*)&sm.xs[ns * 16 + c16][c0 + quad * 8];
            const short4 b2 = *(const short4*)&sm.xs[ns * 16 + c16][c0 + quad * 8 + 4];
            bf16x8 v;
            v[0] = a.x; v[1] = a.y; v[2] = a.z; v[3] = a.w;
            v[4] = b2.x; v[5] = b2.y; v[6] = b2.z; v[7] = b2.w;
            xb[ns] = v;
        }
#pragma unroll
        for (int rs = 0; rs < 5; ++rs)
#pragma unroll
            for (int ns = 0; ns < 2; ++ns)
                acc[rs][ns] = __builtin_amdgcn_mfma_f32_16x16x32_bf16(
                    wa[rs], xb[ns], acc[rs][ns], 0, 0, 0);
    }

    __syncthreads();   // xs dead; osv may alias it now

    // ---- scatter D + bias into LDS result tiles (bf16)
#pragma unroll
    for (int rs = 0; rs < 5; ++rs) {
#pragma unroll
        for (int r = 0; r < 4; ++r) {
            const int rg = w * 80 + rs * 16 + quad * 4 + r;
            const float bias = (rg < 32) ? bq[rg] : (rg < 64) ? bk[rg - 32] : bv[rg - 64];
#pragma unroll
            for (int ns = 0; ns < 2; ++ns) {
                const int n = ns * 16 + c16;
                const u16 h = f2bf(acc[rs][ns][r] + bias);
                if (rg < 64) sm.osqk[n][rg] = h;
                else         sm.osv[rg - 64][n] = h;
            }
        }
    }
    __syncthreads();

    // ---- coalesced global writes
    {
        // q|k: [32 n][32 d] each; threads 0..127 -> q, 128..255 -> k
        u16* dst = (t >= 128) ? kt : qt;
        const int dof = (t >= 128) ? 32 : 0;
        const int o = (t & 127) * 8;                       // flat in [n][32]
        const int n = o >> 5, d = o & 31;
        const bf16x8 v = *(const bf16x8*)&sm.osqk[n][d + dof];
        *(bf16x8*)&dst[((size_t)b * NN + n0) * CQ + o] = v;
    }
#pragma unroll
    for (int it = 0; it < 4; ++it) {
        const int o = it * 2048 + t * 8;                   // flat in [256][32]
        const int c = o >> 5, n = o & 31;
        const bf16x8 v = *(const bf16x8*)&sm.osv[c][n];
        *(bf16x8*)&vv[((size_t)b * CC + c) * NN + n0 + n] = v;
    }
}

// ---------------------------------------------------------------------------
// Kernel 2: flash attention, m64 / 8 waves / n-step 128.
// r3 post-mortem: all pipes <17% at 34% occupancy -> phase-serialization
// overhead dominates (16 barrier-phases x drains/rendezvous/chain latency).
// Fixes: (1) n-step 64->128: 8 phases instead of 16, same total MFMA;
// (2) lgkm-only barrier (raw s_barrier, no vmcnt(0) drain: K/V prefetch
// stays in flight across barriers, compiler auto-waits before use);
// (3) setprio(1) around PV MFMA cluster (phase role diversity across the
// 2 drifting blocks/CU). P swizzle generalized to 16 n-subblocks.
// ---------------------------------------------------------------------------
__global__ __launch_bounds__(512, 4) void attn_kernel(
    const u16* __restrict__ qt, const u16* __restrict__ kt,
    const u16* __restrict__ vv, const float* __restrict__ x,
    const float* __restrict__ gamma_p, float* __restrict__ out)
{
    __shared__ u16 ps16[2][64][136];  // P dbuf, bf16, swizzled (34,816 B)
    __shared__ float lsh[64];         // shared l[m]

    // XCD-aware decode: wg->XCD is round-robin on linear id (id%8).
    const int bid  = blockIdx.x;
    const int xcd  = bid & 7;
    const int slot = bid >> 3;                 // 0..63 within XCD
    const int b    = (xcd << 2) | (slot >> 4); // 4 batches per XCD
    const int m0   = (slot & 15) * 64;

    const int t = threadIdx.x, lane = t & 63, w = t >> 6;  // w 0..7
    const int quad = lane >> 4, c16 = lane & 15;
    const int ch   = c16 >> 3;        // write-side n-subblock low bit
    const int c7   = c16 & 7;
    const int qkey = (c16 >> 2) & 3;  // read-side swizzle key
    const int sm   = w & 3;           // S m-strip (16 rows)
    const int sh   = w >> 2;          // S n-half (64 of 128 cols)
    const int ms0  = w & 3;           // lsum ownership

    // Q A-frag for this wave's S m-strip: Q[m=lane&15][d=quad*8+j]
    const bf16x8 qa = *(const bf16x8*)&qt[((size_t)b * NN + m0 + sm * 16 + c16) * CQ + quad * 8];

    bf16x8 ones;
#pragma unroll
    for (int j = 0; j < 8; ++j) ones[j] = (short)0x3F80;   // bf16 1.0

    f32x4 accO[2][4];                // [cs][ms] of O^T: row=c (c32 strip), col=m
    f32x4 lsum = (f32x4){0.f, 0.f, 0.f, 0.f};   // l for ms0 only
#pragma unroll
    for (int cs = 0; cs < 2; ++cs)
#pragma unroll
        for (int j = 0; j < 4; ++j) accO[cs][j] = (f32x4){0.f, 0.f, 0.f, 0.f};

    const u16* vbase = vv + (size_t)b * CC * NN;   // V[c][n]
    const u16* kbase = kt + (size_t)b * NN * CQ;   // K^T[n][d]

    // pre-issue K frags for step 0 (this wave's 64-n half)
    bf16x8 kb[4];
#pragma unroll
    for (int s = 0; s < 4; ++s)      // B: n-col = lane&15, k=d=quad*8+j
        kb[s] = *(const bf16x8*)&kbase[(size_t)(sh * 64 + s * 16 + c16) * CQ + quad * 8];

    for (int step = 0; step < 8; ++step) {
        const int nbase = step * 128;
        u16* psb = &ps16[step & 1][0][0];

        // V A-frags for this step (c32 strip; consumed post-barrier; the
        // barrier no longer drains vmcnt, so these ride across it)
        bf16x8 va[2][4];
#pragma unroll
        for (int cs = 0; cs < 2; ++cs)
#pragma unroll
            for (int kc = 0; kc < 4; ++kc)   // A: c-row = lane&15, k=n=quad*8+j
                va[cs][kc] = *(const bf16x8*)&vbase[
                    (size_t)(w * 32 + cs * 16 + c16) * NN + nbase + kc * 32 + quad * 8];

        // ---- S strip [16 m][64 n]: wave (sm, sh) owns a unique piece ----
        f32x4 accS[4];
#pragma unroll
        for (int s = 0; s < 4; ++s)
            accS[s] = __builtin_amdgcn_mfma_f32_16x16x32_bf16(
                qa, kb[s], (f32x4){0.f, 0.f, 0.f, 0.f}, 0, 0, 0);

        // ---- P = exp(S) -> bf16 via cvt_pk, swizzled b16 stores ----
        // layout: P[row][nbt(8-wide)] at column-slot (nbt ^ ((row>>2)&3))
        const int rowb = sm * 16 + quad * 4;
#pragma unroll
        for (int s = 0; s < 4; ++s) {
            const int nbt = sh * 8 + 2 * s + ch;       // true n-subblock 0..15
            const int p = nbt ^ quad;                  // stored slot
            u16* pw = &psb[rowb * 136 + p * 8 + c7];
            const float e0 = __expf(accS[s][0]);
            const float e1 = __expf(accS[s][1]);
            const float e2 = __expf(accS[s][2]);
            const float e3 = __expf(accS[s][3]);
            const unsigned p01 = cvt_pk_bf16(e0, e1);
            const unsigned p23 = cvt_pk_bf16(e2, e3);
            pw[0]   = (u16)p01;
            pw[136] = (u16)(p01 >> 16);
            pw[272] = (u16)p23;
            pw[408] = (u16)(p23 >> 16);
        }

        // prefetch K frags for next step (in flight across the barrier)
        if (step < 7) {
#pragma unroll
            for (int s = 0; s < 4; ++s)
                kb[s] = *(const bf16x8*)&kbase[
                    (size_t)(nbase + 128 + sh * 64 + s * 16 + c16) * CQ + quad * 8];
        }

        // lgkm-only barrier: LDS writes visible, global loads NOT drained
        asm volatile("s_waitcnt lgkmcnt(0)" ::: "memory");
        __builtin_amdgcn_s_barrier();
        asm volatile("" ::: "memory");

        // ---- PV: O^T[c][m] += V^T[c][n] · P^T[n][m] ; l[ms0] += 1 · P^T ----
        __builtin_amdgcn_s_setprio(1);
#pragma unroll
        for (int msi = 0; msi < 4; ++msi) {
            bf16x8 pb[4];
#pragma unroll
            for (int kc = 0; kc < 4; ++kc)   // direct b128, swizzled slot
                pb[kc] = *(const bf16x8*)&psb[(msi * 16 + c16) * 136
                                              + (4 * kc + (quad ^ qkey)) * 8];
            if (msi == ms0) {
#pragma unroll
                for (int kc = 0; kc < 4; ++kc)
                    lsum = __builtin_amdgcn_mfma_f32_16x16x32_bf16(ones, pb[kc], lsum, 0, 0, 0);
            }
#pragma unroll
            for (int cs = 0; cs < 2; ++cs)
#pragma unroll
                for (int kc = 0; kc < 4; ++kc)
                    accO[cs][msi] = __builtin_amdgcn_mfma_f32_16x16x32_bf16(
                        va[cs][kc], pb[kc], accO[cs][msi], 0, 0, 0);
        }
        __builtin_amdgcn_s_setprio(0);
    }

    // ---- share l[m] (ms owned by wave w&3==ms, sh==0 half writes) ----
    if (sh == 0 && quad == 0) lsh[ms0 * 16 + c16] = lsum[0];
    __syncthreads();

    // ---- epilogue: out = gamma * O / l + x ----
    const float gamma = gamma_p[0];
#pragma unroll
    for (int ms = 0; ms < 4; ++ms) {
        const float inv = gamma / lsh[ms * 16 + c16];
        const int m = m0 + ms * 16 + c16;
#pragma unroll
        for (int cs = 0; cs < 2; ++cs) {
            const int cbase = w * 32 + cs * 16 + quad * 4;
#pragma unroll
            for (int r = 0; r < 4; ++r) {
                const size_t idx = ((size_t)b * CC + cbase + r) * NN + m;
                out[idx] = accO[cs][ms][r] * inv + x[idx];
            }
        }
    }
}

// ---------------------------------------------------------------------------
extern "C" void kernel_launch(void* const* d_in, const int* in_sizes, int n_in,
                              void* d_out, int out_size, void* d_ws, size_t ws_size,
                              hipStream_t stream)
{
    const float* x  = (const float*)d_in[0];
    const float* Wq = (const float*)d_in[1];
    const float* bq = (const float*)d_in[2];
    const float* Wk = (const float*)d_in[3];
    const float* bk = (const float*)d_in[4];
    const float* Wv = (const float*)d_in[5];
    const float* bv = (const float*)d_in[6];
    const float* gm = (const float*)d_in[7];
    float* out = (float*)d_out;

    // workspace (bf16): qt 2MB | kt 2MB | vv 16MB | wfrag 160KB
    u16* qt    = (u16*)d_ws;
    u16* kt    = qt + (size_t)BB * NN * CQ;
    u16* vv    = kt + (size_t)BB * NN * CQ;
    u16* wfrag = vv + (size_t)BB * CC * NN;

    wpack_kernel<<<320, 256, 0, stream>>>(Wq, Wk, Wv, wfrag);
    dim3 grid(32, BB);
    qkv_kernel<<<grid, 256, 0, stream>>>(x, wfrag, bq, bk, bv, qt, kt, vv);
    attn_kernel<<<512, 512, 0, stream>>>(qt, kt, vv, x, gm, out);
}